// Round 7
// baseline (857.602 us; speedup 1.0000x reference)
//
#include <hip/hip_runtime.h>
#include <hip/hip_cooperative_groups.h>
#include <math.h>

namespace cg = cooperative_groups;

#define NN 5000
#define EE 80000
#define FIN 32
#define DD 64
#define XD 3
#define TD 6
#define PP1 256
#define PP2 32
#define HH 256
#define MM (NN + PP1 + PP2)   // 5288
#define CAP 64
#define NTILES 79             // ceil(5000/64)
#define LOG_SCALE 1.4763057f
#define Y2SCALE (256.f / 5000.f)
#define A2CH 40
#define X2CH 79

// ---------------- workspace layout (bytes) ----------------
#define ACC_OFF   0u           // f32 [2]=ent1 [3]=ent2
#define DEG_OFF   256u
#define Y2A_OFF   20256u
#define X2_OFF    21280u
#define A2_OFF    86816u
#define BM_OFF    348960u      // bitmask -> 3,473,960
#define ZERO_BYTES 3473960u
#define PART_OFF  348960u      // aliases mask (dead after phase A)
#define XW2_OFF   760608u
#define S2_OFF    826144u
#define ZE2_OFF   858912u
#define X3_OFF    924448u
#define Y3_OFF    932640u
#define BUCK_OFF  3473984u
#define ZEP_OFF   4753984u
#define Z_OFF     6033984u
#define S1_OFF    7313984u
#define AS1_OFF   12433984u
#define CQ_OFF    17553984u
#define DRES_OFF  17556032u
#define PA2_OFF   17598336u
#define PX2_OFF   28084096u
#define WS_ROOMY  33261504u

struct KParams {
    const float* x0; const int* adj; const float* t; const float* y;
    const float* Wenc; const float* Wp1; const float* Wp2;
    const float* We1; const float* We2; const float* W1; const float* b1;
    const float* W2; const float* b2;
    float* out; char* ws; int roomy;
};

__device__ __forceinline__ float bsum256(float v, float* red) {
    int t = threadIdx.x;
    red[t] = v; __syncthreads();
    #pragma unroll
    for (int o = 128; o > 0; o >>= 1) {
        if (t < o) red[t] += red[t + o];
        __syncthreads();
    }
    float r = red[0]; __syncthreads();
    return r;
}

// 64x64-tile TN GEMM slice: C(+)= scale * A[k0:k1, tm:+64]^T B[k0:k1, tn:+64]
// A row-stride PP1 (S1). atomicMode: atomicAdd into dst; else float4 store.
__device__ __forceinline__ void gemm_tile(const float* __restrict__ Amat,
        const float* __restrict__ Bmat, int tm, int tn, int k0, int k1, int NB,
        float* __restrict__ dst, int atomicMode, float scale, float* smem) {
    float (*sa)[64] = (float(*)[64])smem;
    float (*sb)[64] = (float(*)[64])(smem + 2048);
    int tid = threadIdx.x;
    int tx = (tid & 15) << 2;
    int ty = (tid >> 4) << 2;
    int r0 = tid >> 4, c0 = (tid & 15) << 2;
    int r1 = r0 + 16;
    float acc[4][4] = {};
    const float4 z4 = make_float4(0.f, 0.f, 0.f, 0.f);
    for (int kb = k0; kb < k1; kb += 32) {
        int ka0 = kb + r0, ka1 = kb + r1;
        *(float4*)&sa[r0][c0] = (ka0 < k1) ? *(const float4*)&Amat[ka0 * PP1 + tm + c0] : z4;
        *(float4*)&sa[r1][c0] = (ka1 < k1) ? *(const float4*)&Amat[ka1 * PP1 + tm + c0] : z4;
        *(float4*)&sb[r0][c0] = (ka0 < k1) ? *(const float4*)&Bmat[ka0 * NB + tn + c0] : z4;
        *(float4*)&sb[r1][c0] = (ka1 < k1) ? *(const float4*)&Bmat[ka1 * NB + tn + c0] : z4;
        __syncthreads();
        #pragma unroll
        for (int kk = 0; kk < 32; ++kk) {
            float4 av = *(const float4*)&sa[kk][ty];
            float4 bv = *(const float4*)&sb[kk][tx];
            acc[0][0] = fmaf(av.x, bv.x, acc[0][0]);
            acc[0][1] = fmaf(av.x, bv.y, acc[0][1]);
            acc[0][2] = fmaf(av.x, bv.z, acc[0][2]);
            acc[0][3] = fmaf(av.x, bv.w, acc[0][3]);
            acc[1][0] = fmaf(av.y, bv.x, acc[1][0]);
            acc[1][1] = fmaf(av.y, bv.y, acc[1][1]);
            acc[1][2] = fmaf(av.y, bv.z, acc[1][2]);
            acc[1][3] = fmaf(av.y, bv.w, acc[1][3]);
            acc[2][0] = fmaf(av.z, bv.x, acc[2][0]);
            acc[2][1] = fmaf(av.z, bv.y, acc[2][1]);
            acc[2][2] = fmaf(av.z, bv.z, acc[2][2]);
            acc[2][3] = fmaf(av.z, bv.w, acc[2][3]);
            acc[3][0] = fmaf(av.w, bv.x, acc[3][0]);
            acc[3][1] = fmaf(av.w, bv.y, acc[3][1]);
            acc[3][2] = fmaf(av.w, bv.z, acc[3][2]);
            acc[3][3] = fmaf(av.w, bv.w, acc[3][3]);
        }
        __syncthreads();
    }
    if (atomicMode) {
        #pragma unroll
        for (int i = 0; i < 4; ++i)
            #pragma unroll
            for (int j = 0; j < 4; ++j)
                atomicAdd(&dst[(tm + ty + i) * NB + tn + tx + j], acc[i][j] * scale);
    } else {
        #pragma unroll
        for (int i = 0; i < 4; ++i)
            *(float4*)&dst[(tm + ty + i) * NB + tn + tx] =
                make_float4(acc[i][0] * scale, acc[i][1] * scale,
                            acc[i][2] * scale, acc[i][3] * scale);
    }
}

// decode 8 rows starting at i0 (works for z / x2 / x3 ranges)
__device__ __forceinline__ void decoder_rows(
        int i0, const float* __restrict__ z, const float* __restrict__ x2,
        const float* __restrict__ x3, const float* __restrict__ y,
        const float* __restrict__ y2acc, const float* __restrict__ y3,
        const float* __restrict__ W1, const float* __restrict__ W2,
        const float* __restrict__ b2, const float* __restrict__ cq,
        float* __restrict__ dres, float* smem) {
    float (*zr)[DD] = (float(*)[DD])smem;
    float (*rw)[3][4] = (float(*)[3][4])(smem + 512);
    int t = threadIdx.x;
    #pragma unroll
    for (int e = t; e < 512; e += 256) {
        int r = e >> 6, d = e & 63;
        int i = i0 + r;
        float v;
        if (i < NN) v = z[i * DD + d];
        else if (i < NN + PP1) v = x2[(i - NN) * DD + d];
        else v = x3[(i - NN - PP1) * DD + d];
        zr[r][d] = v;
    }
    __syncthreads();
    int h = t;
    float c0 = cq[h];
    float a[8];
    #pragma unroll
    for (int r = 0; r < 8; ++r) a[r] = c0;
    #pragma unroll 8
    for (int k = 0; k < DD; ++k) {
        float w = W1[(TD + XD + k) * HH + h];
        #pragma unroll
        for (int r = 0; r < 8; ++r) a[r] = fmaf(zr[r][k], w, a[r]);
    }
    float w2h = W2[h], w1h = W1[h], qh = cq[HH + h];
    float pu[8], pg[8], pl[8];
    #pragma unroll
    for (int r = 0; r < 8; ++r) {
        float th = tanhf(a[r]);
        float g1 = 1.f - th * th;
        pu[r] = w2h * th;
        pg[r] = w2h * g1 * w1h;
        pl[r] = w2h * (-2.f * th * g1) * qh;
    }
    #pragma unroll
    for (int o = 32; o > 0; o >>= 1) {
        #pragma unroll
        for (int r = 0; r < 8; ++r) {
            pu[r] += __shfl_xor(pu[r], o);
            pg[r] += __shfl_xor(pg[r], o);
            pl[r] += __shfl_xor(pl[r], o);
        }
    }
    int wave = t >> 6, lane = t & 63;
    if (lane == 0) {
        #pragma unroll
        for (int r = 0; r < 8; ++r) {
            rw[r][0][wave] = pu[r];
            rw[r][1][wave] = pg[r];
            rw[r][2][wave] = pl[r];
        }
    }
    __syncthreads();
    if (t < 8) {
        int r = t, i = i0 + r;
        float su = rw[r][0][0] + rw[r][0][1] + rw[r][0][2] + rw[r][0][3];
        float sg = rw[r][1][0] + rw[r][1][1] + rw[r][1][2] + rw[r][1][3];
        float sl = rw[r][2][0] + rw[r][2][1] + rw[r][2][2] + rw[r][2][3];
        float u = su + b2[0];
        float yv = (i < NN) ? y[i]
                 : (i < NN + PP1) ? y2acc[i - NN] * Y2SCALE
                 : y3[i - NN - PP1];
        float du = u - yv;
        float res = sg - sl;
        dres[i * 2] = du * du;
        dres[i * 2 + 1] = res * res;
    }
}

__global__ __launch_bounds__(256, 4) void mega(KParams p) {
    __shared__ __align__(16) float smem[8192];   // 32 KB, reused per phase
    int tid = threadIdx.x;
    char* ws = p.ws;
    float* acc   = (float*)(ws + ACC_OFF);
    int*   deg   = (int*)(ws + DEG_OFF);
    float* y2acc = (float*)(ws + Y2A_OFF);
    float* x2    = (float*)(ws + X2_OFF);
    float* A2    = (float*)(ws + A2_OFF);
    unsigned int* mask = (unsigned int*)(ws + BM_OFF);
    float* part  = (float*)(ws + PART_OFF);
    float* XW2   = (float*)(ws + XW2_OFF);
    float* S2    = (float*)(ws + S2_OFF);
    float* ze2   = (float*)(ws + ZE2_OFF);
    float* x3    = (float*)(ws + X3_OFF);
    float* y3    = (float*)(ws + Y3_OFF);
    int*   buck  = (int*)(ws + BUCK_OFF);
    float* zep   = (float*)(ws + ZEP_OFF);
    float* z     = (float*)(ws + Z_OFF);
    float* S1    = (float*)(ws + S1_OFF);
    float* AS1   = (float*)(ws + AS1_OFF);
    float* cq    = (float*)(ws + CQ_OFF);
    float* dres  = (float*)(ws + DRES_OFF);
    float* PA2   = (float*)(ws + PA2_OFF);
    float* PX2   = (float*)(ws + PX2_OFF);
    cg::grid_group gg = cg::this_grid();

    // ---- Phase A: encoder z | edge dedupe | prep cq ----
    for (int vb = blockIdx.x; vb < 1564; vb += gridDim.x) {
        if (vb < 1250) {
            float (*wx)[DD] = (float(*)[DD])smem;
            float (*xr)[FIN] = (float(*)[FIN])(smem + FIN * DD);
            int i0 = vb << 2;
            int j = tid & 63;
            #pragma unroll
            for (int m = 0; m < 8; ++m) {
                int k = (tid >> 6) + (m << 2);
                wx[k][j] = p.Wenc[k * (DD + XD) + j];
            }
            if (tid < 128) xr[tid >> 5][tid & 31] = p.x0[(i0 + (tid >> 5)) * FIN + (tid & 31)];
            __syncthreads();
            int r = tid >> 6;
            float s = 0.f;
            #pragma unroll
            for (int k = 0; k < FIN; ++k) s = fmaf(xr[r][k], wx[k][j], s);
            z[(i0 + r) * DD + j] = tanhf(s) * LOG_SCALE;
        } else if (vb < 1563) {
            int e = (vb - 1250) * 256 + tid;
            if (e < EE) {
                int i = p.adj[e], jj = p.adj[EE + e];
                unsigned int key = (unsigned int)(i * NN + jj);
                unsigned int bit = 1u << (key & 31u);
                unsigned int old = atomicOr(&mask[key >> 5], bit);
                if (!(old & bit)) {
                    int slot = atomicAdd(&deg[i], 1);
                    if (slot < CAP) buck[i * CAP + slot] = jj;
                }
            }
        } else {
            float* te = smem;
            if (tid == 0) {
                float t0 = p.t[0];
                te[0] = t0 / 1e2f;
                te[1] = t0 / 1e3f;
                te[2] = t0 / 1e4f;
                te[3] = logf(t0 * 100.f + 1.f);
                te[4] = logf(t0 * 10.f + 1.f);
                te[5] = logf(t0 + 1.f);
            }
            __syncthreads();
            int h = tid;
            float c = p.b1[h];
            #pragma unroll
            for (int j2 = 0; j2 < TD; ++j2) c = fmaf(te[j2], p.W1[j2 * HH + h], c);
            float q = 0.f;
            #pragma unroll
            for (int j2 = 1; j2 < TD + XD; ++j2) { float w = p.W1[j2 * HH + h]; q = fmaf(w, w, q); }
            cq[h] = c;
            cq[HH + h] = q;
        }
        __syncthreads();
    }
    gg.sync();

    // ---- Phase B: S1 logits GEMM + softmax partials | gather_embed zep ----
    for (int vb = blockIdx.x; vb < NTILES * 4 + 1250; vb += gridDim.x) {
        if (vb < NTILES * 4) {
            float (*sa)[64] = (float(*)[64])smem;
            float (*sb)[64] = (float(*)[64])(smem + 4096);
            int tm = (vb >> 2) << 6;
            int tn = (vb & 3) << 6;
            int r0 = tid >> 4, c0 = (tid & 15) << 2;
            const float4 zero4 = make_float4(0.f, 0.f, 0.f, 0.f);
            #pragma unroll
            for (int m = 0; m < 4; ++m) {
                int row = r0 + (m << 4);
                int gr = tm + row;
                *(float4*)&sa[row][c0] = (gr < NN) ? *(const float4*)&z[gr * DD + c0] : zero4;
                *(float4*)&sb[row][c0] = *(const float4*)&p.Wp1[row * PP1 + tn + c0];
            }
            __syncthreads();
            int tx = (tid & 15) << 2;
            int ty = (tid >> 4) << 2;
            float acr[4][4] = {};
            #pragma unroll
            for (int kk = 0; kk < 64; ++kk) {
                float a0 = sa[ty + 0][kk];
                float a1 = sa[ty + 1][kk];
                float a2 = sa[ty + 2][kk];
                float a3 = sa[ty + 3][kk];
                float4 bv = *(const float4*)&sb[kk][tx];
                acr[0][0] = fmaf(a0, bv.x, acr[0][0]);
                acr[0][1] = fmaf(a0, bv.y, acr[0][1]);
                acr[0][2] = fmaf(a0, bv.z, acr[0][2]);
                acr[0][3] = fmaf(a0, bv.w, acr[0][3]);
                acr[1][0] = fmaf(a1, bv.x, acr[1][0]);
                acr[1][1] = fmaf(a1, bv.y, acr[1][1]);
                acr[1][2] = fmaf(a1, bv.z, acr[1][2]);
                acr[1][3] = fmaf(a1, bv.w, acr[1][3]);
                acr[2][0] = fmaf(a2, bv.x, acr[2][0]);
                acr[2][1] = fmaf(a2, bv.y, acr[2][1]);
                acr[2][2] = fmaf(a2, bv.z, acr[2][2]);
                acr[2][3] = fmaf(a2, bv.w, acr[2][3]);
                acr[3][0] = fmaf(a3, bv.x, acr[3][0]);
                acr[3][1] = fmaf(a3, bv.y, acr[3][1]);
                acr[3][2] = fmaf(a3, bv.z, acr[3][2]);
                acr[3][3] = fmaf(a3, bv.w, acr[3][3]);
            }
            #pragma unroll
            for (int i2 = 0; i2 < 4; ++i2)
                #pragma unroll
                for (int j = 0; j < 4; ++j) acr[i2][j] *= LOG_SCALE;
            #pragma unroll
            for (int i2 = 0; i2 < 4; ++i2) {
                int gr = tm + ty + i2;
                if (gr < NN)
                    *(float4*)&S1[gr * PP1 + tn + tx] =
                        make_float4(acr[i2][0], acr[i2][1], acr[i2][2], acr[i2][3]);
            }
            int nvalid = NN - (tm + ty);
            nvalid = (nvalid < 0) ? 0 : (nvalid > 4 ? 4 : nvalid);
            float vm[4], vs[4];
            #pragma unroll
            for (int j = 0; j < 4; ++j) {
                float m = -3.0e38f;
                #pragma unroll
                for (int i2 = 0; i2 < 4; ++i2) if (i2 < nvalid) m = fmaxf(m, acr[i2][j]);
                float s = 0.f;
                #pragma unroll
                for (int i2 = 0; i2 < 4; ++i2) if (i2 < nvalid) s += expf(acr[i2][j] - m);
                vm[j] = m; vs[j] = s;
            }
            __syncthreads();
            float* redm = smem;
            float* reds = smem + 1024;
            int g = tid >> 4;
            #pragma unroll
            for (int j = 0; j < 4; ++j) {
                redm[g * 64 + tx + j] = vm[j];
                reds[g * 64 + tx + j] = vs[j];
            }
            __syncthreads();
            if (tid < 64) {
                float M = -3.0e38f, S = 0.f;
                #pragma unroll
                for (int g2 = 0; g2 < 16; ++g2) {
                    float m2 = redm[g2 * 64 + tid], s2 = reds[g2 * 64 + tid];
                    float Mn = fmaxf(M, m2);
                    S = S * expf(M - Mn) + s2 * expf(m2 - Mn);
                    M = Mn;
                }
                int rt = tm >> 6;
                part[rt * 512 + tn + tid] = M;
                part[rt * 512 + 256 + tn + tid] = S;
            }
        } else {
            float (*zs)[DD] = (float(*)[DD])smem;
            int w = tid >> 6, d = tid & 63;
            int i = ((vb - NTILES * 4) << 2) + w;
            int n = min(deg[i], CAP);
            const int* bk = buck + i * CAP;
            float a0 = 0.f, a1 = 0.f, a2 = 0.f, a3 = 0.f;
            int s = 0;
            for (; s + 4 <= n; s += 4) {
                a0 += z[bk[s] * DD + d];
                a1 += z[bk[s + 1] * DD + d];
                a2 += z[bk[s + 2] * DD + d];
                a3 += z[bk[s + 3] * DD + d];
            }
            for (; s < n; ++s) a0 += z[bk[s] * DD + d];
            zs[w][d] = (a0 + a1) + (a2 + a3);
            __syncthreads();
            float a = 0.f;
            #pragma unroll
            for (int k = 0; k < DD; ++k) a = fmaf(zs[w][k], p.We1[k * DD + d], a);
            zep[i * DD + d] = tanhf(a);
        }
        __syncthreads();
    }
    gg.sync();

    // ---- Phase C: S1 softmax normalize + entropy + y2acc ----
    for (int vb = blockIdx.x; vb < NTILES * 4; vb += gridDim.x) {
        float* red = smem;
        float (*ybuf)[64] = (float(*)[64])(smem + 256);
        float* cst = smem + 512;
        int rt = vb % NTILES, ct = vb / NTILES;
        int lc = tid & 63, q = tid >> 6;
        int c = (ct << 6) + lc;
        float M = -3.0e38f, Sv = 0.f;
        for (int ch = q; ch < NTILES; ch += 4) {
            float m2 = part[ch * 512 + c];
            float s2 = part[ch * 512 + 256 + c];
            float Mn = fmaxf(M, m2);
            Sv = Sv * expf(M - Mn) + s2 * expf(m2 - Mn);
            M = Mn;
        }
        red[tid] = M; ybuf[q][lc] = Sv;
        __syncthreads();
        if (q == 0) {
            float Mm = red[lc], Ss = ybuf[0][lc];
            #pragma unroll
            for (int g = 1; g < 4; ++g) {
                float m2 = red[g * 64 + lc], s2 = ybuf[g][lc];
                float Mn = fmaxf(Mm, m2);
                Ss = Ss * expf(Mm - Mn) + s2 * expf(m2 - Mn);
                Mm = Mn;
            }
            cst[lc] = Mm + logf(Ss);
        }
        __syncthreads();
        float mxlns = cst[lc];
        float en = 0.f, ys = 0.f;
        #pragma unroll
        for (int k = 0; k < 16; ++k) {
            int r = (rt << 6) + (k << 2) + q;
            if (r < NN) {
                float v = S1[r * PP1 + c];
                float s = expf(v - mxlns);
                S1[r * PP1 + c] = s;
                en += s * (mxlns - v);
                ys = fmaf(s, p.y[r], ys);
            }
        }
        __syncthreads();
        ybuf[q][lc] = ys;
        en = bsum256(en, red);
        if (tid == 0) atomicAdd(&acc[2], en);
        if (q == 0) atomicAdd(&y2acc[c], ybuf[0][lc] + ybuf[1][lc] + ybuf[2][lc] + ybuf[3][lc]);
        __syncthreads();
    }
    gg.sync();

    // ---- Phase D: gather_as | x2 split-K GEMM | decoder z-rows ----
    for (int vb = blockIdx.x; vb < 5000 + 316 + 625; vb += gridDim.x) {
        if (vb < 5000) {
            int i = vb, c = tid;
            int n = min(deg[i], CAP);
            const int* bk = buck + i * CAP;
            float a0 = 0.f, a1 = 0.f, a2 = 0.f, a3 = 0.f;
            int s = 0;
            for (; s + 4 <= n; s += 4) {
                a0 += S1[bk[s] * PP1 + c];
                a1 += S1[bk[s + 1] * PP1 + c];
                a2 += S1[bk[s + 2] * PP1 + c];
                a3 += S1[bk[s + 3] * PP1 + c];
            }
            for (; s < n; ++s) a0 += S1[bk[s] * PP1 + c];
            AS1[i * PP1 + c] = (a0 + a1) + (a2 + a3);
        } else if (vb < 5316) {
            int vb2 = vb - 5000;
            int tile = vb2 & 3, chunk = vb2 >> 2;
            int k0 = chunk * 64, k1 = min(k0 + 64, NN);
            gemm_tile(S1, zep, tile << 6, 0, k0, k1, DD,
                      p.roomy ? PX2 + chunk * (PP1 * DD) : x2,
                      !p.roomy, p.roomy ? 1.f : Y2SCALE, smem);
        } else {
            decoder_rows((vb - 5316) << 3, z, x2, x3, p.y, y2acc, y3,
                         p.W1, p.W2, p.b2, cq, dres, smem);
        }
        __syncthreads();
    }
    gg.sync();

    // ---- Phase E: A2 split-K GEMM | x2 partial reduce ----
    for (int vb = blockIdx.x; vb < 704; vb += gridDim.x) {
        if (vb < 640) {
            int tile = vb & 15, chunk = vb >> 4;
            int k0 = chunk * 128, k1 = min(k0 + 128, NN);
            gemm_tile(S1, AS1, (tile >> 2) << 6, (tile & 3) << 6, k0, k1, PP1,
                      p.roomy ? PA2 + chunk * (PP1 * PP1) : A2,
                      !p.roomy, 1.f, smem);
        } else if (p.roomy) {
            int idx = (vb - 640) * 256 + tid;
            float s = 0.f;
            #pragma unroll 8
            for (int c = 0; c < X2CH; ++c) s += PX2[c * (PP1 * DD) + idx];
            x2[idx] = s * Y2SCALE;
        }
        __syncthreads();
    }
    gg.sync();

    // ---- Phase F: A2 partial reduce | XW2 + S2 logits | decoder x2-rows ----
    for (int vb = blockIdx.x; vb < 384; vb += gridDim.x) {
        if (vb < 256) {
            if (p.roomy) {
                int idx = vb * 256 + tid;
                float s = 0.f;
                #pragma unroll 8
                for (int c = 0; c < A2CH; ++c) s += PA2[c * (PP1 * PP1) + idx];
                A2[idx] = s;
            }
        } else if (vb < 352) {
            int gid = (vb - 256) * 256 + tid;
            if (gid < PP1 * DD) {
                int i = gid >> 6, j = gid & 63;
                float s = 0.f;
                #pragma unroll
                for (int k = 0; k < DD; ++k) s = fmaf(x2[i * DD + k], p.We2[k * DD + j], s);
                XW2[gid] = s;
            } else {
                int e = gid - PP1 * DD;
                int i = e >> 5, j = e & 31;
                float s = 0.f;
                #pragma unroll
                for (int k = 0; k < DD; ++k) s = fmaf(x2[i * DD + k], p.Wp2[k * PP2 + j], s);
                S2[e] = s * LOG_SCALE;
            }
        } else {
            decoder_rows(5000 + ((vb - 352) << 3), z, x2, x3, p.y, y2acc, y3,
                         p.W1, p.W2, p.b2, cq, dres, smem);
        }
        __syncthreads();
    }
    gg.sync();

    // ---- Phase H: S2 softmax (+ent2+y3) | ze2 = tanh(A2@XW2) ----
    for (int vb = blockIdx.x; vb < 96; vb += gridDim.x) {
        if (vb < PP2) {
            float* red = smem;
            int pcol = vb;
            float l = S2[tid * PP2 + pcol];
            red[tid] = l; __syncthreads();
            #pragma unroll
            for (int o = 128; o > 0; o >>= 1) {
                if (tid < o) red[tid] = fmaxf(red[tid], red[tid + o]);
                __syncthreads();
            }
            float mx = red[0]; __syncthreads();
            float ex = expf(l - mx);
            float sum = bsum256(ex, red);
            float lns = logf(sum), inv = 1.f / sum;
            float s = ex * inv;
            S2[tid * PP2 + pcol] = s;
            float en = s * (mx + lns - l);
            float ys = s * y2acc[tid];
            en = bsum256(en, red);
            ys = bsum256(ys, red);
            if (tid == 0) {
                atomicAdd(&acc[3], en);
                y3[pcol] = ys * ((32.f / 256.f) * Y2SCALE);
            }
        } else {
            int gid = (vb - PP2) * 256 + tid;
            int i = gid >> 6, j = gid & 63;
            const float* a = A2 + i * PP1;
            float s = 0.f;
            #pragma unroll 16
            for (int k = 0; k < PP1; ++k) s = fmaf(a[k], XW2[k * DD + j], s);
            ze2[gid] = tanhf(s);
        }
        __syncthreads();
    }
    gg.sync();

    // ---- Phase I: x3 pool ----
    for (int vb = blockIdx.x; vb < PP2; vb += gridDim.x) {
        float (*pr)[64] = (float(*)[64])smem;
        int j = vb;
        int d = tid & 63, q = tid >> 6;
        float a = 0.f;
        #pragma unroll 4
        for (int i = q * 64; i < q * 64 + 64; ++i)
            a = fmaf(S2[i * PP2 + j], ze2[i * DD + d], a);
        pr[q][d] = a;
        __syncthreads();
        if (q == 0) x3[j * DD + d] = (pr[0][d] + pr[1][d] + pr[2][d] + pr[3][d]) * (32.f / 256.f);
        __syncthreads();
    }
    gg.sync();

    // ---- Phase K (block 0): decoder x3-rows + final loss ----
    if (blockIdx.x == 0) {
        for (int vb = 0; vb < 4; ++vb) {
            decoder_rows(5256 + (vb << 3), z, x2, x3, p.y, y2acc, y3,
                         p.W1, p.W2, p.b2, cq, dres, smem);
            __syncthreads();
        }
        float* red = smem;
        float sd = 0.f, sp = 0.f;
        for (int i = tid; i < MM; i += 256) {
            sd += dres[i * 2];
            sp += dres[i * 2 + 1];
        }
        sd = bsum256(sd, red);
        sp = bsum256(sp, red);
        if (tid == 0)
            p.out[0] = sd * (1.f / MM) + sp * (1.f / MM)
                     + acc[2] * (1.f / (float)(NN * PP1)) + acc[3] * (1.f / (float)(PP1 * PP2));
    }
}

extern "C" void kernel_launch(void* const* d_in, const int* in_sizes, int n_in,
                              void* d_out, int out_size, void* d_ws, size_t ws_size,
                              hipStream_t stream) {
    KParams kp;
    kp.x0   = (const float*)d_in[0];
    kp.adj  = (const int*)d_in[1];
    kp.t    = (const float*)d_in[2];
    kp.y    = (const float*)d_in[3];
    kp.Wenc = (const float*)d_in[4];
    kp.Wp1  = (const float*)d_in[5];
    kp.Wp2  = (const float*)d_in[6];
    kp.We1  = (const float*)d_in[7];
    kp.We2  = (const float*)d_in[8];
    kp.W1   = (const float*)d_in[9];
    kp.b1   = (const float*)d_in[10];
    kp.W2   = (const float*)d_in[11];
    kp.b2   = (const float*)d_in[12];
    kp.out  = (float*)d_out;
    kp.ws   = (char*)d_ws;
    kp.roomy = (ws_size >= WS_ROOMY) ? 1 : 0;

    hipMemsetAsync(d_ws, 0, ZERO_BYTES, stream);

    int nb = 0;
    if (hipOccupancyMaxActiveBlocksPerMultiprocessor(&nb, (const void*)mega, 256, 0) != hipSuccess || nb < 1)
        nb = 2;
    int grid = nb * 256;          // 256 CUs on MI355X
    if (grid > 1024) grid = 1024;

    void* args[] = { &kp };
    hipLaunchCooperativeKernel((const void*)mega, dim3(grid), dim3(256), args, 0, stream);
}

// Round 9
// 325.167 us; speedup vs baseline: 2.6374x; 2.6374x over previous
//
#include <hip/hip_runtime.h>
#include <math.h>

#define NN 5000
#define EE 80000
#define FIN 32
#define DD 64
#define XD 3
#define TD 6
#define PP1 256
#define PP2 32
#define HH 256
#define MM (NN + PP1 + PP2)   // 5288
#define CAP 64
#define NTILES 79             // ceil(5000/64)
#define LOG_SCALE 1.4763057f
#define Y2SCALE (256.f / 5000.f)
#define A2CH 40
#define X2CH 79

// ---------------- workspace layout (bytes) ----------------
#define ACC_OFF   0u           // f32 [2]=ent1 [3]=ent2
#define CNT_OFF   64u          // int counter for tail kernel
#define DEG_OFF   256u
#define Y2A_OFF   20256u
#define X2_OFF    21280u
#define A2_OFF    86816u
#define BM_OFF    348960u      // bitmask -> 3,473,960
#define ZERO_BYTES 3473960u
#define PART_OFF  348960u      // aliases mask (dead after stage0)
#define XW2_OFF   760608u
#define S2_OFF    826144u
#define ZE2_OFF   858912u
#define Y3_OFF    932640u
#define BUCK_OFF  3473984u
#define ZEP_OFF   4753984u
#define Z_OFF     6033984u
#define S1_OFF    7313984u
#define AS1_OFF   12433984u
#define CQ_OFF    17553984u
#define DRES_OFF  17556032u
#define PA2_OFF   17598336u
#define PX2_OFF   28084096u
#define WS_ROOMY  33261504u

__device__ __forceinline__ float bsum256(float v, float* red) {
    int t = threadIdx.x;
    red[t] = v; __syncthreads();
    #pragma unroll
    for (int o = 128; o > 0; o >>= 1) {
        if (t < o) red[t] += red[t + o];
        __syncthreads();
    }
    float r = red[0]; __syncthreads();
    return r;
}

// 64x64-tile TN GEMM slice: dst(+)= scale * A[k0:k1, tm:+64]^T B[k0:k1, tn:+64]
__device__ void gemm_tile(const float* Amat, const float* Bmat,
        int tm, int tn, int k0, int k1, int NB,
        float* dst, int atomicMode, float scale, float* smem) {
    float (*sa)[64] = (float(*)[64])smem;
    float (*sb)[64] = (float(*)[64])(smem + 2048);
    int tid = threadIdx.x;
    int tx = (tid & 15) << 2;
    int ty = (tid >> 4) << 2;
    int r0 = tid >> 4, c0 = (tid & 15) << 2;
    int r1 = r0 + 16;
    float acc[4][4] = {};
    const float4 z4 = make_float4(0.f, 0.f, 0.f, 0.f);
    for (int kb = k0; kb < k1; kb += 32) {
        int ka0 = kb + r0, ka1 = kb + r1;
        *(float4*)&sa[r0][c0] = (ka0 < k1) ? *(const float4*)&Amat[ka0 * PP1 + tm + c0] : z4;
        *(float4*)&sa[r1][c0] = (ka1 < k1) ? *(const float4*)&Amat[ka1 * PP1 + tm + c0] : z4;
        *(float4*)&sb[r0][c0] = (ka0 < k1) ? *(const float4*)&Bmat[ka0 * NB + tn + c0] : z4;
        *(float4*)&sb[r1][c0] = (ka1 < k1) ? *(const float4*)&Bmat[ka1 * NB + tn + c0] : z4;
        __syncthreads();
        #pragma unroll
        for (int kk = 0; kk < 32; ++kk) {
            float4 av = *(const float4*)&sa[kk][ty];
            float4 bv = *(const float4*)&sb[kk][tx];
            acc[0][0] = fmaf(av.x, bv.x, acc[0][0]);
            acc[0][1] = fmaf(av.x, bv.y, acc[0][1]);
            acc[0][2] = fmaf(av.x, bv.z, acc[0][2]);
            acc[0][3] = fmaf(av.x, bv.w, acc[0][3]);
            acc[1][0] = fmaf(av.y, bv.x, acc[1][0]);
            acc[1][1] = fmaf(av.y, bv.y, acc[1][1]);
            acc[1][2] = fmaf(av.y, bv.z, acc[1][2]);
            acc[1][3] = fmaf(av.y, bv.w, acc[1][3]);
            acc[2][0] = fmaf(av.z, bv.x, acc[2][0]);
            acc[2][1] = fmaf(av.z, bv.y, acc[2][1]);
            acc[2][2] = fmaf(av.z, bv.z, acc[2][2]);
            acc[2][3] = fmaf(av.z, bv.w, acc[2][3]);
            acc[3][0] = fmaf(av.w, bv.x, acc[3][0]);
            acc[3][1] = fmaf(av.w, bv.y, acc[3][1]);
            acc[3][2] = fmaf(av.w, bv.z, acc[3][2]);
            acc[3][3] = fmaf(av.w, bv.w, acc[3][3]);
        }
        __syncthreads();
    }
    if (atomicMode) {
        #pragma unroll
        for (int i = 0; i < 4; ++i)
            #pragma unroll
            for (int j = 0; j < 4; ++j)
                atomicAdd(&dst[(tm + ty + i) * NB + tn + tx + j], acc[i][j] * scale);
    } else {
        #pragma unroll
        for (int i = 0; i < 4; ++i)
            *(float4*)&dst[(tm + ty + i) * NB + tn + tx] =
                make_float4(acc[i][0] * scale, acc[i][1] * scale,
                            acc[i][2] * scale, acc[i][3] * scale);
    }
}

// decode 8 consecutive rows: src = 8x64 row block, ysrc = 8 targets (scaled by yscale).
// writes dres[(i0+r)*2 .. +1]
__device__ void decoder_rows(const float* src, const float* ysrc, float yscale, int i0,
        const float* W1, const float* W2, const float* b2, const float* cq,
        float* dres, float* smem) {
    float (*zr)[DD] = (float(*)[DD])smem;
    float (*rw)[3][4] = (float(*)[3][4])(smem + 512);
    int t = threadIdx.x;
    zr[t >> 6][t & 63] = src[t];
    zr[(t >> 6) + 4][t & 63] = src[t + 256];
    __syncthreads();
    int h = t;
    float c0 = cq[h];
    float a[8];
    #pragma unroll
    for (int r = 0; r < 8; ++r) a[r] = c0;
    #pragma unroll 8
    for (int k = 0; k < DD; ++k) {
        float w = W1[(TD + XD + k) * HH + h];
        #pragma unroll
        for (int r = 0; r < 8; ++r) a[r] = fmaf(zr[r][k], w, a[r]);
    }
    float w2h = W2[h], w1h = W1[h], qh = cq[HH + h];
    float pu[8], pg[8], pl[8];
    #pragma unroll
    for (int r = 0; r < 8; ++r) {
        float th = tanhf(a[r]);
        float g1 = 1.f - th * th;
        pu[r] = w2h * th;
        pg[r] = w2h * g1 * w1h;
        pl[r] = w2h * (-2.f * th * g1) * qh;
    }
    #pragma unroll
    for (int o = 32; o > 0; o >>= 1) {
        #pragma unroll
        for (int r = 0; r < 8; ++r) {
            pu[r] += __shfl_xor(pu[r], o);
            pg[r] += __shfl_xor(pg[r], o);
            pl[r] += __shfl_xor(pl[r], o);
        }
    }
    int wave = t >> 6, lane = t & 63;
    if (lane == 0) {
        #pragma unroll
        for (int r = 0; r < 8; ++r) {
            rw[r][0][wave] = pu[r];
            rw[r][1][wave] = pg[r];
            rw[r][2][wave] = pl[r];
        }
    }
    __syncthreads();
    if (t < 8) {
        int r = t;
        float su = rw[r][0][0] + rw[r][0][1] + rw[r][0][2] + rw[r][0][3];
        float sg = rw[r][1][0] + rw[r][1][1] + rw[r][1][2] + rw[r][1][3];
        float sl = rw[r][2][0] + rw[r][2][1] + rw[r][2][2] + rw[r][2][3];
        float u = su + b2[0];
        float du = u - ysrc[r] * yscale;
        float res = sg - sl;
        dres[(i0 + r) * 2] = du * du;
        dres[(i0 + r) * 2 + 1] = res * res;
    }
    __syncthreads();
}

// fused: encoder GEMM | edge dedupe | prep c/q
__global__ __launch_bounds__(256) void stage0(
        const float* __restrict__ x0, const float* __restrict__ Wenc,
        float* __restrict__ z,
        const int* __restrict__ adj, unsigned int* __restrict__ mask,
        int* __restrict__ bucket, int* __restrict__ deg,
        const float* __restrict__ t, const float* __restrict__ W1,
        const float* __restrict__ b1, float* __restrict__ cq) {
    __shared__ __align__(16) float smem[FIN * DD + 4 * FIN];
    int b = blockIdx.x;
    int tid = threadIdx.x;
    if (b < 1250) {
        float (*wx)[DD] = (float(*)[DD])smem;
        float (*xr)[FIN] = (float(*)[FIN])(smem + FIN * DD);
        int i0 = b << 2;
        int j = tid & 63;
        #pragma unroll
        for (int m = 0; m < 8; ++m) {
            int k = (tid >> 6) + (m << 2);
            wx[k][j] = Wenc[k * (DD + XD) + j];
        }
        if (tid < 128) xr[tid >> 5][tid & 31] = x0[(i0 + (tid >> 5)) * FIN + (tid & 31)];
        __syncthreads();
        int r = tid >> 6;
        float s = 0.f;
        #pragma unroll
        for (int k = 0; k < FIN; ++k) s = fmaf(xr[r][k], wx[k][j], s);
        z[(i0 + r) * DD + j] = tanhf(s) * LOG_SCALE;
    } else if (b < 1563) {
        int e = (b - 1250) * 256 + tid;
        if (e < EE) {
            int i = adj[e], jj = adj[EE + e];
            unsigned int key = (unsigned int)(i * NN + jj);
            unsigned int bit = 1u << (key & 31u);
            unsigned int old = atomicOr(&mask[key >> 5], bit);
            if (!(old & bit)) {
                int slot = atomicAdd(&deg[i], 1);
                if (slot < CAP) bucket[i * CAP + slot] = jj;
            }
        }
    } else {
        float* te = smem;
        if (tid == 0) {
            float t0 = t[0];
            te[0] = t0 / 1e2f;
            te[1] = t0 / 1e3f;
            te[2] = t0 / 1e4f;
            te[3] = logf(t0 * 100.f + 1.f);
            te[4] = logf(t0 * 10.f + 1.f);
            te[5] = logf(t0 + 1.f);
        }
        __syncthreads();
        int h = tid;
        float c = b1[h];
        #pragma unroll
        for (int j2 = 0; j2 < TD; ++j2) c = fmaf(te[j2], W1[j2 * HH + h], c);
        float q = 0.f;
        #pragma unroll
        for (int j2 = 1; j2 < TD + XD; ++j2) { float w = W1[j2 * HH + h]; q = fmaf(w, w, q); }
        cq[h] = c;
        cq[HH + h] = q;
    }
}

// fused: S1 logits GEMM + softmax partials | gather_z + embed
__global__ __launch_bounds__(256) void stage1(
        const float* __restrict__ z, const float* __restrict__ Wp1,
        float* __restrict__ S1, float* __restrict__ part,
        const int* __restrict__ bucket, const int* __restrict__ deg,
        const float* __restrict__ We1, float* __restrict__ zep) {
    __shared__ __align__(16) float smem[2 * 64 * 64];
    int b = blockIdx.x;
    int tid = threadIdx.x;
    if (b < NTILES * 4) {
        float (*sa)[64] = (float(*)[64])smem;
        float (*sb)[64] = (float(*)[64])(smem + 4096);
        int tm = (b >> 2) << 6;
        int tn = (b & 3) << 6;
        int r0 = tid >> 4, c0 = (tid & 15) << 2;
        const float4 zero4 = make_float4(0.f, 0.f, 0.f, 0.f);
        #pragma unroll
        for (int m = 0; m < 4; ++m) {
            int row = r0 + (m << 4);
            int gr = tm + row;
            *(float4*)&sa[row][c0] = (gr < NN) ? *(const float4*)&z[gr * DD + c0] : zero4;
            *(float4*)&sb[row][c0] = *(const float4*)&Wp1[row * PP1 + tn + c0];
        }
        __syncthreads();
        int tx = (tid & 15) << 2;
        int ty = (tid >> 4) << 2;
        float acr[4][4] = {};
        #pragma unroll
        for (int kk = 0; kk < 64; ++kk) {
            float a0 = sa[ty + 0][kk];
            float a1 = sa[ty + 1][kk];
            float a2 = sa[ty + 2][kk];
            float a3 = sa[ty + 3][kk];
            float4 bv = *(const float4*)&sb[kk][tx];
            acr[0][0] = fmaf(a0, bv.x, acr[0][0]);
            acr[0][1] = fmaf(a0, bv.y, acr[0][1]);
            acr[0][2] = fmaf(a0, bv.z, acr[0][2]);
            acr[0][3] = fmaf(a0, bv.w, acr[0][3]);
            acr[1][0] = fmaf(a1, bv.x, acr[1][0]);
            acr[1][1] = fmaf(a1, bv.y, acr[1][1]);
            acr[1][2] = fmaf(a1, bv.z, acr[1][2]);
            acr[1][3] = fmaf(a1, bv.w, acr[1][3]);
            acr[2][0] = fmaf(a2, bv.x, acr[2][0]);
            acr[2][1] = fmaf(a2, bv.y, acr[2][1]);
            acr[2][2] = fmaf(a2, bv.z, acr[2][2]);
            acr[2][3] = fmaf(a2, bv.w, acr[2][3]);
            acr[3][0] = fmaf(a3, bv.x, acr[3][0]);
            acr[3][1] = fmaf(a3, bv.y, acr[3][1]);
            acr[3][2] = fmaf(a3, bv.z, acr[3][2]);
            acr[3][3] = fmaf(a3, bv.w, acr[3][3]);
        }
        #pragma unroll
        for (int i2 = 0; i2 < 4; ++i2)
            #pragma unroll
            for (int j = 0; j < 4; ++j) acr[i2][j] *= LOG_SCALE;
        #pragma unroll
        for (int i2 = 0; i2 < 4; ++i2) {
            int gr = tm + ty + i2;
            if (gr < NN)
                *(float4*)&S1[gr * PP1 + tn + tx] =
                    make_float4(acr[i2][0], acr[i2][1], acr[i2][2], acr[i2][3]);
        }
        int nvalid = NN - (tm + ty);
        nvalid = (nvalid < 0) ? 0 : (nvalid > 4 ? 4 : nvalid);
        float vm[4], vs[4];
        #pragma unroll
        for (int j = 0; j < 4; ++j) {
            float m = -3.0e38f;
            #pragma unroll
            for (int i2 = 0; i2 < 4; ++i2) if (i2 < nvalid) m = fmaxf(m, acr[i2][j]);
            float s = 0.f;
            #pragma unroll
            for (int i2 = 0; i2 < 4; ++i2) if (i2 < nvalid) s += expf(acr[i2][j] - m);
            vm[j] = m; vs[j] = s;
        }
        __syncthreads();
        float* redm = smem;
        float* reds = smem + 1024;
        int g = tid >> 4;
        #pragma unroll
        for (int j = 0; j < 4; ++j) {
            redm[g * 64 + tx + j] = vm[j];
            reds[g * 64 + tx + j] = vs[j];
        }
        __syncthreads();
        if (tid < 64) {
            float M = -3.0e38f, S = 0.f;
            #pragma unroll
            for (int g2 = 0; g2 < 16; ++g2) {
                float m2 = redm[g2 * 64 + tid], s2 = reds[g2 * 64 + tid];
                float Mn = fmaxf(M, m2);
                S = S * expf(M - Mn) + s2 * expf(m2 - Mn);
                M = Mn;
            }
            int rt = tm >> 6;
            part[rt * 512 + tn + tid] = M;
            part[rt * 512 + 256 + tn + tid] = S;
        }
    } else {
        float (*zs)[DD] = (float(*)[DD])smem;
        int w = tid >> 6, d = tid & 63;
        int i = ((b - NTILES * 4) << 2) + w;
        int n = min(deg[i], CAP);
        const int* bk = bucket + i * CAP;
        float a0 = 0.f, a1 = 0.f, a2 = 0.f, a3 = 0.f;
        int s = 0;
        for (; s + 4 <= n; s += 4) {
            a0 += z[bk[s] * DD + d];
            a1 += z[bk[s + 1] * DD + d];
            a2 += z[bk[s + 2] * DD + d];
            a3 += z[bk[s + 3] * DD + d];
        }
        for (; s < n; ++s) a0 += z[bk[s] * DD + d];
        zs[w][d] = (a0 + a1) + (a2 + a3);
        __syncthreads();
        float a = 0.f;
        #pragma unroll
        for (int k = 0; k < DD; ++k) a = fmaf(zs[w][k], We1[k * DD + d], a);
        zep[i * DD + d] = tanhf(a);
    }
}

// normalize S1 + entropy + y2 accumulation (chunk-combine inline)
__global__ __launch_bounds__(256) void smax_norm(
        float* __restrict__ S, const float* __restrict__ part,
        const float* __restrict__ y, float* __restrict__ y2acc,
        float* __restrict__ ent) {
    __shared__ float red[256];
    __shared__ float ybuf[4][64];
    __shared__ float cst[64];
    int rt = blockIdx.x % NTILES, ct = blockIdx.x / NTILES;
    int lc = threadIdx.x & 63, q = threadIdx.x >> 6;
    int c = (ct << 6) + lc;
    float M = -3.0e38f, Sv = 0.f;
    for (int ch = q; ch < NTILES; ch += 4) {
        float m2 = part[ch * 512 + c];
        float s2 = part[ch * 512 + 256 + c];
        float Mn = fmaxf(M, m2);
        Sv = Sv * expf(M - Mn) + s2 * expf(m2 - Mn);
        M = Mn;
    }
    red[threadIdx.x] = M; ybuf[q][lc] = Sv;
    __syncthreads();
    if (q == 0) {
        float Mm = red[lc], Ss = ybuf[0][lc];
        #pragma unroll
        for (int g = 1; g < 4; ++g) {
            float m2 = red[g * 64 + lc], s2 = ybuf[g][lc];
            float Mn = fmaxf(Mm, m2);
            Ss = Ss * expf(Mm - Mn) + s2 * expf(m2 - Mn);
            Mm = Mn;
        }
        cst[lc] = Mm + logf(Ss);
    }
    __syncthreads();
    float mxlns = cst[lc];
    float en = 0.f, ys = 0.f;
    #pragma unroll
    for (int k = 0; k < 16; ++k) {
        int r = (rt << 6) + (k << 2) + q;
        if (r < NN) {
            float v = S[r * PP1 + c];
            float s = expf(v - mxlns);
            S[r * PP1 + c] = s;
            en += s * (mxlns - v);
            ys = fmaf(s, y[r], ys);
        }
    }
    __syncthreads();
    ybuf[q][lc] = ys;
    en = bsum256(en, red);
    if (threadIdx.x == 0) atomicAdd(ent, en);
    if (q == 0) atomicAdd(&y2acc[c], ybuf[0][lc] + ybuf[1][lc] + ybuf[2][lc] + ybuf[3][lc]);
}

// fuseD: gather_as (0..4999) | x2 split-K GEMM (5000..5315) | decoder z-rows (5316..5940)
__global__ __launch_bounds__(256) void fuseD(
        const int* __restrict__ bucket, const int* __restrict__ deg,
        const float* __restrict__ S1, float* __restrict__ AS1,
        const float* __restrict__ zep, float* __restrict__ PX2,
        float* __restrict__ x2,
        const float* __restrict__ z, const float* __restrict__ y,
        const float* __restrict__ W1, const float* __restrict__ W2,
        const float* __restrict__ b2, const float* __restrict__ cq,
        float* __restrict__ dres, int roomy) {
    __shared__ __align__(16) float smem[4096];
    int b = blockIdx.x;
    if (b < NN) {
        int i = b, c = threadIdx.x;
        int n = min(deg[i], CAP);
        const int* bk = bucket + i * CAP;
        float a0 = 0.f, a1 = 0.f, a2 = 0.f, a3 = 0.f;
        int s = 0;
        for (; s + 4 <= n; s += 4) {
            a0 += S1[bk[s] * PP1 + c];
            a1 += S1[bk[s + 1] * PP1 + c];
            a2 += S1[bk[s + 2] * PP1 + c];
            a3 += S1[bk[s + 3] * PP1 + c];
        }
        for (; s < n; ++s) a0 += S1[bk[s] * PP1 + c];
        AS1[i * PP1 + c] = (a0 + a1) + (a2 + a3);
    } else if (b < NN + 316) {
        int vb2 = b - NN;
        int tile = vb2 & 3, chunk = vb2 >> 2;
        int k0 = chunk * 64, k1 = min(k0 + 64, NN);
        float* dst = roomy ? (PX2 + chunk * (PP1 * DD)) : x2;
        gemm_tile(S1, zep, tile << 6, 0, k0, k1, DD, dst, 1 - roomy,
                  roomy ? 1.f : Y2SCALE, smem);
    } else {
        int r8 = b - (NN + 316);
        decoder_rows(z + (r8 << 3) * DD, y + (r8 << 3), 1.f, r8 << 3,
                     W1, W2, b2, cq, dres, smem);
    }
}

// fuseE: A2 split-K GEMM (0..639) | x2 partial reduce (640..703)
__global__ __launch_bounds__(256) void fuseE(
        const float* __restrict__ S1, const float* __restrict__ AS1,
        float* __restrict__ PA2, float* __restrict__ A2,
        const float* __restrict__ PX2, float* __restrict__ x2, int roomy) {
    __shared__ __align__(16) float smem[4096];
    int b = blockIdx.x;
    if (b < 640) {
        int tile = b & 15, chunk = b >> 4;
        int k0 = chunk * 128, k1 = min(k0 + 128, NN);
        float* dst = roomy ? (PA2 + chunk * (PP1 * PP1)) : A2;
        gemm_tile(S1, AS1, (tile >> 2) << 6, (tile & 3) << 6, k0, k1, PP1,
                  dst, 1 - roomy, 1.f, smem);
    } else if (roomy) {
        int idx = (b - 640) * 256 + threadIdx.x;
        float s = 0.f;
        #pragma unroll 8
        for (int c = 0; c < X2CH; ++c) s += PX2[c * (PP1 * DD) + idx];
        x2[idx] = s * Y2SCALE;
    }
}

// fuseF: A2 partial reduce (0..255) | XW2 + S2 logits (256..351) | decoder x2-rows (352..383)
__global__ __launch_bounds__(256) void fuseF(
        const float* __restrict__ PA2, float* __restrict__ A2,
        const float* __restrict__ x2, const float* __restrict__ We2,
        const float* __restrict__ Wp2, float* __restrict__ XW2,
        float* __restrict__ S2,
        const float* __restrict__ y2acc,
        const float* __restrict__ W1, const float* __restrict__ W2,
        const float* __restrict__ b2, const float* __restrict__ cq,
        float* __restrict__ dres, int roomy) {
    __shared__ __align__(16) float smem[640];
    int b = blockIdx.x;
    int tid = threadIdx.x;
    if (b < 256) {
        if (roomy) {
            int idx = b * 256 + tid;
            float s = 0.f;
            #pragma unroll 8
            for (int c = 0; c < A2CH; ++c) s += PA2[c * (PP1 * PP1) + idx];
            A2[idx] = s;
        }
    } else if (b < 352) {
        int gid = (b - 256) * 256 + tid;
        if (gid < PP1 * DD) {
            int i = gid >> 6, j = gid & 63;
            float s = 0.f;
            #pragma unroll
            for (int k = 0; k < DD; ++k) s = fmaf(x2[i * DD + k], We2[k * DD + j], s);
            XW2[gid] = s;
        } else {
            int e = gid - PP1 * DD;
            int i = e >> 5, j = e & 31;
            float s = 0.f;
            #pragma unroll
            for (int k = 0; k < DD; ++k) s = fmaf(x2[i * DD + k], Wp2[k * PP2 + j], s);
            S2[e] = s * LOG_SCALE;
        }
    } else {
        int r8 = b - 352;
        decoder_rows(x2 + (r8 << 3) * DD, y2acc + (r8 << 3), Y2SCALE, NN + (r8 << 3),
                     W1, W2, b2, cq, dres, smem);
    }
}

// fuseH: S2 softmax (+ent2+y3) (0..31) | ze2 = tanh(A2@XW2) (32..95)
__global__ __launch_bounds__(256) void fuseH(
        float* __restrict__ S2, float* __restrict__ ent,
        const float* __restrict__ y2acc, float* __restrict__ y3,
        const float* __restrict__ A2, const float* __restrict__ XW2,
        float* __restrict__ ze2) {
    __shared__ float red[256];
    int t = threadIdx.x;
    if (blockIdx.x < PP2) {
        int p = blockIdx.x;
        float l = S2[t * PP2 + p];
        red[t] = l; __syncthreads();
        #pragma unroll
        for (int o = 128; o > 0; o >>= 1) {
            if (t < o) red[t] = fmaxf(red[t], red[t + o]);
            __syncthreads();
        }
        float mx = red[0]; __syncthreads();
        float ex = expf(l - mx);
        float sum = bsum256(ex, red);
        float lns = logf(sum), inv = 1.f / sum;
        float s = ex * inv;
        S2[t * PP2 + p] = s;
        float en = s * (mx + lns - l);
        float ys = s * y2acc[t];
        en = bsum256(en, red);
        ys = bsum256(ys, red);
        if (t == 0) {
            atomicAdd(ent, en);
            y3[p] = ys * ((32.f / 256.f) * Y2SCALE);
        }
    } else {
        int gid = (blockIdx.x - PP2) * 256 + t;
        int i = gid >> 6, j = gid & 63;
        const float* a = A2 + i * PP1;
        float s = 0.f;
        #pragma unroll 16
        for (int k = 0; k < PP1; ++k) s = fmaf(a[k], XW2[k * DD + j], s);
        ze2[gid] = tanhf(s);
    }
}

// tail (4 blocks): compute 8 x3 rows in LDS, decode them, last block reduces the loss
__global__ __launch_bounds__(256) void tail(
        const float* __restrict__ S2, const float* __restrict__ ze2,
        const float* __restrict__ y3,
        const float* __restrict__ W1, const float* __restrict__ W2,
        const float* __restrict__ b2, const float* __restrict__ cq,
        float* __restrict__ dres, int* __restrict__ cnt,
        const float* __restrict__ acc, float* __restrict__ out) {
    __shared__ __align__(16) float smem[1152];   // [0..511] x3 rows, [512..1119] decoder scratch
    __shared__ int lastflag;
    int t = threadIdx.x;
    int jbase = blockIdx.x << 3;
    #pragma unroll
    for (int kk = 0; kk < 2; ++kk) {
        int idx = t + kk * 256;
        int jl = idx >> 6, d = idx & 63;
        int j = jbase + jl;
        float a = 0.f;
        for (int i = 0; i < PP1; ++i)
            a = fmaf(S2[i * PP2 + j], ze2[i * DD + d], a);
        smem[idx] = a * (32.f / 256.f);
    }
    __syncthreads();
    decoder_rows(smem, y3 + jbase, 1.f, NN + PP1 + jbase,
                 W1, W2, b2, cq, dres, smem + 512);
    if (t < 8) __threadfence();
    __syncthreads();
    if (t == 0) lastflag = atomicAdd(cnt, 1);
    __syncthreads();
    if (lastflag == 3) {
        __threadfence();
        float* red = smem;
        float sd = 0.f, sp = 0.f;
        for (int i = t; i < MM; i += 256) {
            sd += dres[i * 2];
            sp += dres[i * 2 + 1];
        }
        sd = bsum256(sd, red);
        sp = bsum256(sp, red);
        if (t == 0)
            out[0] = sd * (1.f / MM) + sp * (1.f / MM)
                   + acc[2] * (1.f / (float)(NN * PP1)) + acc[3] * (1.f / (float)(PP1 * PP2));
    }
}

extern "C" void kernel_launch(void* const* d_in, const int* in_sizes, int n_in,
                              void* d_out, int out_size, void* d_ws, size_t ws_size,
                              hipStream_t stream) {
    const float* x0   = (const float*)d_in[0];
    const int*   adj  = (const int*)d_in[1];
    const float* t    = (const float*)d_in[2];
    const float* y    = (const float*)d_in[3];
    const float* Wenc = (const float*)d_in[4];
    const float* Wp1  = (const float*)d_in[5];
    const float* Wp2  = (const float*)d_in[6];
    const float* We1  = (const float*)d_in[7];
    const float* We2  = (const float*)d_in[8];
    const float* W1   = (const float*)d_in[9];
    const float* b1   = (const float*)d_in[10];
    const float* W2   = (const float*)d_in[11];
    const float* b2   = (const float*)d_in[12];

    char* ws = (char*)d_ws;
    float* acc   = (float*)(ws + ACC_OFF);
    int*   cnt   = (int*)(ws + CNT_OFF);
    int*   deg   = (int*)(ws + DEG_OFF);
    float* y2acc = (float*)(ws + Y2A_OFF);
    float* x2    = (float*)(ws + X2_OFF);
    float* A2    = (float*)(ws + A2_OFF);
    unsigned int* mask = (unsigned int*)(ws + BM_OFF);
    float* part  = (float*)(ws + PART_OFF);
    float* XW2   = (float*)(ws + XW2_OFF);
    float* S2    = (float*)(ws + S2_OFF);
    float* ze2   = (float*)(ws + ZE2_OFF);
    float* y3    = (float*)(ws + Y3_OFF);
    int*   buck  = (int*)(ws + BUCK_OFF);
    float* zep   = (float*)(ws + ZEP_OFF);
    float* z     = (float*)(ws + Z_OFF);
    float* S1    = (float*)(ws + S1_OFF);
    float* AS1   = (float*)(ws + AS1_OFF);
    float* cq    = (float*)(ws + CQ_OFF);
    float* dres  = (float*)(ws + DRES_OFF);
    float* PA2   = (float*)(ws + PA2_OFF);
    float* PX2   = (float*)(ws + PX2_OFF);
    int roomy = (ws_size >= WS_ROOMY) ? 1 : 0;

    hipMemsetAsync(ws, 0, ZERO_BYTES, stream);

    stage0<<<1564, 256, 0, stream>>>(x0, Wenc, z, adj, mask, buck, deg, t, W1, b1, cq);
    stage1<<<NTILES * 4 + NN / 4, 256, 0, stream>>>(z, Wp1, S1, part, buck, deg, We1, zep);
    smax_norm<<<NTILES * 4, 256, 0, stream>>>(S1, part, y, y2acc, &acc[2]);
    fuseD<<<NN + 316 + 625, 256, 0, stream>>>(buck, deg, S1, AS1, zep, PX2, x2,
                                              z, y, W1, W2, b2, cq, dres, roomy);
    fuseE<<<704, 256, 0, stream>>>(S1, AS1, PA2, A2, PX2, x2, roomy);
    fuseF<<<384, 256, 0, stream>>>(PA2, A2, x2, We2, Wp2, XW2, S2, y2acc,
                                   W1, W2, b2, cq, dres, roomy);
    fuseH<<<96, 256, 0, stream>>>(S2, &acc[3], y2acc, y3, A2, XW2, ze2);
    tail<<<4, 256, 0, stream>>>(S2, ze2, y3, W1, W2, b2, cq,
                                dres, cnt, acc, (float*)d_out);
}

// Round 10
// 293.933 us; speedup vs baseline: 2.9177x; 1.1063x over previous
//
#include <hip/hip_runtime.h>
#include <math.h>

#define NN 5000
#define EE 80000
#define FIN 32
#define DD 64
#define XD 3
#define TD 6
#define PP1 256
#define PP2 32
#define HH 256
#define MM (NN + PP1 + PP2)   // 5288
#define CAP 64
#define NTILES 79             // ceil(5000/64)
#define LOG_SCALE 1.4763057f
#define Y2SCALE (256.f / 5000.f)
#define A2CH 40
#define X2CH 79

// ---------------- workspace layout (bytes) ----------------
#define ACC_OFF   0u           // f32 [2]=ent1 [3]=ent2
#define CNT_OFF   64u          // int counter for tail kernel
#define DEG_OFF   256u
#define Y2A_OFF   20256u
#define X2_OFF    21280u
#define A2_OFF    86816u
#define BM_OFF    348960u      // bitmask -> 3,473,960
#define ZERO_BYTES 3473960u
// aliases inside BM region (bitmask dead after stage0):
#define PART_OFF  348960u      // [79][2][256] f32 -> 510752
#define CSTAT_OFF 510752u      // [256] -> 511776
#define XW2_OFF   760608u
#define S2_OFF    826144u
#define ZE2_OFF   858912u
#define Y3_OFF    932640u
// non-zeroed:
#define BUCK_OFF  3473984u
#define ZEP_OFF   4753984u
#define Z_OFF     6033984u
#define S1_OFF    7313984u
#define AS1_OFF   12433984u
#define CQ_OFF    17553984u
#define DRES_OFF  17556032u
#define PA2_OFF   17598336u
#define PX2_OFF   28084096u
#define WS_ROOMY  33261504u

__device__ __forceinline__ float bsum256(float v, float* red) {
    int t = threadIdx.x;
    red[t] = v; __syncthreads();
    #pragma unroll
    for (int o = 128; o > 0; o >>= 1) {
        if (t < o) red[t] += red[t + o];
        __syncthreads();
    }
    float r = red[0]; __syncthreads();
    return r;
}

// 64x64-tile TN GEMM slice: dst(+)= scale * A[k0:k1, tm:+64]^T B[k0:k1, tn:+64]
__device__ void gemm_tile(const float* Amat, const float* Bmat,
        int tm, int tn, int k0, int k1, int NB,
        float* dst, int atomicMode, float scale, float* smem) {
    float (*sa)[64] = (float(*)[64])smem;
    float (*sb)[64] = (float(*)[64])(smem + 2048);
    int tid = threadIdx.x;
    int tx = (tid & 15) << 2;
    int ty = (tid >> 4) << 2;
    int r0 = tid >> 4, c0 = (tid & 15) << 2;
    int r1 = r0 + 16;
    float acc[4][4] = {};
    const float4 z4 = make_float4(0.f, 0.f, 0.f, 0.f);
    for (int kb = k0; kb < k1; kb += 32) {
        int ka0 = kb + r0, ka1 = kb + r1;
        *(float4*)&sa[r0][c0] = (ka0 < k1) ? *(const float4*)&Amat[ka0 * PP1 + tm + c0] : z4;
        *(float4*)&sa[r1][c0] = (ka1 < k1) ? *(const float4*)&Amat[ka1 * PP1 + tm + c0] : z4;
        *(float4*)&sb[r0][c0] = (ka0 < k1) ? *(const float4*)&Bmat[ka0 * NB + tn + c0] : z4;
        *(float4*)&sb[r1][c0] = (ka1 < k1) ? *(const float4*)&Bmat[ka1 * NB + tn + c0] : z4;
        __syncthreads();
        #pragma unroll
        for (int kk = 0; kk < 32; ++kk) {
            float4 av = *(const float4*)&sa[kk][ty];
            float4 bv = *(const float4*)&sb[kk][tx];
            acc[0][0] = fmaf(av.x, bv.x, acc[0][0]);
            acc[0][1] = fmaf(av.x, bv.y, acc[0][1]);
            acc[0][2] = fmaf(av.x, bv.z, acc[0][2]);
            acc[0][3] = fmaf(av.x, bv.w, acc[0][3]);
            acc[1][0] = fmaf(av.y, bv.x, acc[1][0]);
            acc[1][1] = fmaf(av.y, bv.y, acc[1][1]);
            acc[1][2] = fmaf(av.y, bv.z, acc[1][2]);
            acc[1][3] = fmaf(av.y, bv.w, acc[1][3]);
            acc[2][0] = fmaf(av.z, bv.x, acc[2][0]);
            acc[2][1] = fmaf(av.z, bv.y, acc[2][1]);
            acc[2][2] = fmaf(av.z, bv.z, acc[2][2]);
            acc[2][3] = fmaf(av.z, bv.w, acc[2][3]);
            acc[3][0] = fmaf(av.w, bv.x, acc[3][0]);
            acc[3][1] = fmaf(av.w, bv.y, acc[3][1]);
            acc[3][2] = fmaf(av.w, bv.z, acc[3][2]);
            acc[3][3] = fmaf(av.w, bv.w, acc[3][3]);
        }
        __syncthreads();
    }
    if (atomicMode) {
        #pragma unroll
        for (int i = 0; i < 4; ++i)
            #pragma unroll
            for (int j = 0; j < 4; ++j)
                atomicAdd(&dst[(tm + ty + i) * NB + tn + tx + j], acc[i][j] * scale);
    } else {
        #pragma unroll
        for (int i = 0; i < 4; ++i)
            *(float4*)&dst[(tm + ty + i) * NB + tn + tx] =
                make_float4(acc[i][0] * scale, acc[i][1] * scale,
                            acc[i][2] * scale, acc[i][3] * scale);
    }
}

// decode 8 consecutive rows: src = 8x64 row block, ysrc = 8 targets (scaled by yscale)
__device__ void decoder_rows(const float* src, const float* ysrc, float yscale, int i0,
        const float* W1, const float* W2, const float* b2, const float* cq,
        float* dres, float* smem) {
    float (*zr)[DD] = (float(*)[DD])smem;
    float (*rw)[3][4] = (float(*)[3][4])(smem + 512);
    int t = threadIdx.x;
    zr[t >> 6][t & 63] = src[t];
    zr[(t >> 6) + 4][t & 63] = src[t + 256];
    __syncthreads();
    int h = t;
    float c0 = cq[h];
    float a[8];
    #pragma unroll
    for (int r = 0; r < 8; ++r) a[r] = c0;
    #pragma unroll 8
    for (int k = 0; k < DD; ++k) {
        float w = W1[(TD + XD + k) * HH + h];
        #pragma unroll
        for (int r = 0; r < 8; ++r) a[r] = fmaf(zr[r][k], w, a[r]);
    }
    float w2h = W2[h], w1h = W1[h], qh = cq[HH + h];
    float pu[8], pg[8], pl[8];
    #pragma unroll
    for (int r = 0; r < 8; ++r) {
        float th = tanhf(a[r]);
        float g1 = 1.f - th * th;
        pu[r] = w2h * th;
        pg[r] = w2h * g1 * w1h;
        pl[r] = w2h * (-2.f * th * g1) * qh;
    }
    #pragma unroll
    for (int o = 32; o > 0; o >>= 1) {
        #pragma unroll
        for (int r = 0; r < 8; ++r) {
            pu[r] += __shfl_xor(pu[r], o);
            pg[r] += __shfl_xor(pg[r], o);
            pl[r] += __shfl_xor(pl[r], o);
        }
    }
    int wave = t >> 6, lane = t & 63;
    if (lane == 0) {
        #pragma unroll
        for (int r = 0; r < 8; ++r) {
            rw[r][0][wave] = pu[r];
            rw[r][1][wave] = pg[r];
            rw[r][2][wave] = pl[r];
        }
    }
    __syncthreads();
    if (t < 8) {
        int r = t;
        float su = rw[r][0][0] + rw[r][0][1] + rw[r][0][2] + rw[r][0][3];
        float sg = rw[r][1][0] + rw[r][1][1] + rw[r][1][2] + rw[r][1][3];
        float sl = rw[r][2][0] + rw[r][2][1] + rw[r][2][2] + rw[r][2][3];
        float u = su + b2[0];
        float du = u - ysrc[r] * yscale;
        float res = sg - sl;
        dres[(i0 + r) * 2] = du * du;
        dres[(i0 + r) * 2 + 1] = res * res;
    }
    __syncthreads();
}

// fused: encoder GEMM | edge dedupe | prep c/q
__global__ __launch_bounds__(256) void stage0(
        const float* __restrict__ x0, const float* __restrict__ Wenc,
        float* __restrict__ z,
        const int* __restrict__ adj, unsigned int* __restrict__ mask,
        int* __restrict__ bucket, int* __restrict__ deg,
        const float* __restrict__ t, const float* __restrict__ W1,
        const float* __restrict__ b1, float* __restrict__ cq) {
    __shared__ __align__(16) float smem[FIN * DD + 4 * FIN];
    int b = blockIdx.x;
    int tid = threadIdx.x;
    if (b < 1250) {
        float (*wx)[DD] = (float(*)[DD])smem;
        float (*xr)[FIN] = (float(*)[FIN])(smem + FIN * DD);
        int i0 = b << 2;
        int j = tid & 63;
        #pragma unroll
        for (int m = 0; m < 8; ++m) {
            int k = (tid >> 6) + (m << 2);
            wx[k][j] = Wenc[k * (DD + XD) + j];
        }
        if (tid < 128) xr[tid >> 5][tid & 31] = x0[(i0 + (tid >> 5)) * FIN + (tid & 31)];
        __syncthreads();
        int r = tid >> 6;
        float s = 0.f;
        #pragma unroll
        for (int k = 0; k < FIN; ++k) s = fmaf(xr[r][k], wx[k][j], s);
        z[(i0 + r) * DD + j] = tanhf(s) * LOG_SCALE;
    } else if (b < 1563) {
        int e = (b - 1250) * 256 + tid;
        if (e < EE) {
            int i = adj[e], jj = adj[EE + e];
            unsigned int key = (unsigned int)(i * NN + jj);
            unsigned int bit = 1u << (key & 31u);
            unsigned int old = atomicOr(&mask[key >> 5], bit);
            if (!(old & bit)) {
                int slot = atomicAdd(&deg[i], 1);
                if (slot < CAP) bucket[i * CAP + slot] = jj;
            }
        }
    } else {
        float* te = smem;
        if (tid == 0) {
            float t0 = t[0];
            te[0] = t0 / 1e2f;
            te[1] = t0 / 1e3f;
            te[2] = t0 / 1e4f;
            te[3] = logf(t0 * 100.f + 1.f);
            te[4] = logf(t0 * 10.f + 1.f);
            te[5] = logf(t0 + 1.f);
        }
        __syncthreads();
        int h = tid;
        float c = b1[h];
        #pragma unroll
        for (int j2 = 0; j2 < TD; ++j2) c = fmaf(te[j2], W1[j2 * HH + h], c);
        float q = 0.f;
        #pragma unroll
        for (int j2 = 1; j2 < TD + XD; ++j2) { float w = W1[j2 * HH + h]; q = fmaf(w, w, q); }
        cq[h] = c;
        cq[HH + h] = q;
    }
}

// fused: S1 logits GEMM + softmax partials | gather_z + embed
__global__ __launch_bounds__(256) void stage1(
        const float* __restrict__ z, const float* __restrict__ Wp1,
        float* __restrict__ S1, float* __restrict__ part,
        const int* __restrict__ bucket, const int* __restrict__ deg,
        const float* __restrict__ We1, float* __restrict__ zep) {
    __shared__ __align__(16) float smem[2 * 64 * 64];
    int b = blockIdx.x;
    int tid = threadIdx.x;
    if (b < NTILES * 4) {
        float (*sa)[64] = (float(*)[64])smem;
        float (*sb)[64] = (float(*)[64])(smem + 4096);
        int tm = (b >> 2) << 6;
        int tn = (b & 3) << 6;
        int r0 = tid >> 4, c0 = (tid & 15) << 2;
        const float4 zero4 = make_float4(0.f, 0.f, 0.f, 0.f);
        #pragma unroll
        for (int m = 0; m < 4; ++m) {
            int row = r0 + (m << 4);
            int gr = tm + row;
            *(float4*)&sa[row][c0] = (gr < NN) ? *(const float4*)&z[gr * DD + c0] : zero4;
            *(float4*)&sb[row][c0] = *(const float4*)&Wp1[row * PP1 + tn + c0];
        }
        __syncthreads();
        int tx = (tid & 15) << 2;
        int ty = (tid >> 4) << 2;
        float acr[4][4] = {};
        #pragma unroll
        for (int kk = 0; kk < 64; ++kk) {
            float a0 = sa[ty + 0][kk];
            float a1 = sa[ty + 1][kk];
            float a2 = sa[ty + 2][kk];
            float a3 = sa[ty + 3][kk];
            float4 bv = *(const float4*)&sb[kk][tx];
            acr[0][0] = fmaf(a0, bv.x, acr[0][0]);
            acr[0][1] = fmaf(a0, bv.y, acr[0][1]);
            acr[0][2] = fmaf(a0, bv.z, acr[0][2]);
            acr[0][3] = fmaf(a0, bv.w, acr[0][3]);
            acr[1][0] = fmaf(a1, bv.x, acr[1][0]);
            acr[1][1] = fmaf(a1, bv.y, acr[1][1]);
            acr[1][2] = fmaf(a1, bv.z, acr[1][2]);
            acr[1][3] = fmaf(a1, bv.w, acr[1][3]);
            acr[2][0] = fmaf(a2, bv.x, acr[2][0]);
            acr[2][1] = fmaf(a2, bv.y, acr[2][1]);
            acr[2][2] = fmaf(a2, bv.z, acr[2][2]);
            acr[2][3] = fmaf(a2, bv.w, acr[2][3]);
            acr[3][0] = fmaf(a3, bv.x, acr[3][0]);
            acr[3][1] = fmaf(a3, bv.y, acr[3][1]);
            acr[3][2] = fmaf(a3, bv.z, acr[3][2]);
            acr[3][3] = fmaf(a3, bv.w, acr[3][3]);
        }
        #pragma unroll
        for (int i2 = 0; i2 < 4; ++i2)
            #pragma unroll
            for (int j = 0; j < 4; ++j) acr[i2][j] *= LOG_SCALE;
        #pragma unroll
        for (int i2 = 0; i2 < 4; ++i2) {
            int gr = tm + ty + i2;
            if (gr < NN)
                *(float4*)&S1[gr * PP1 + tn + tx] =
                    make_float4(acr[i2][0], acr[i2][1], acr[i2][2], acr[i2][3]);
        }
        int nvalid = NN - (tm + ty);
        nvalid = (nvalid < 0) ? 0 : (nvalid > 4 ? 4 : nvalid);
        float vm[4], vs[4];
        #pragma unroll
        for (int j = 0; j < 4; ++j) {
            float m = -3.0e38f;
            #pragma unroll
            for (int i2 = 0; i2 < 4; ++i2) if (i2 < nvalid) m = fmaxf(m, acr[i2][j]);
            float s = 0.f;
            #pragma unroll
            for (int i2 = 0; i2 < 4; ++i2) if (i2 < nvalid) s += expf(acr[i2][j] - m);
            vm[j] = m; vs[j] = s;
        }
        __syncthreads();
        float* redm = smem;
        float* reds = smem + 1024;
        int g = tid >> 4;
        #pragma unroll
        for (int j = 0; j < 4; ++j) {
            redm[g * 64 + tx + j] = vm[j];
            reds[g * 64 + tx + j] = vs[j];
        }
        __syncthreads();
        if (tid < 64) {
            float M = -3.0e38f, S = 0.f;
            #pragma unroll
            for (int g2 = 0; g2 < 16; ++g2) {
                float m2 = redm[g2 * 64 + tid], s2 = reds[g2 * 64 + tid];
                float Mn = fmaxf(M, m2);
                S = S * expf(M - Mn) + s2 * expf(m2 - Mn);
                M = Mn;
            }
            int rt = tm >> 6;
            part[rt * 512 + tn + tid] = M;
            part[rt * 512 + 256 + tn + tid] = S;
        }
    } else {
        float (*zs)[DD] = (float(*)[DD])smem;
        int w = tid >> 6, d = tid & 63;
        int i = ((b - NTILES * 4) << 2) + w;
        int n = min(deg[i], CAP);
        const int* bk = bucket + i * CAP;
        float a0 = 0.f, a1 = 0.f, a2 = 0.f, a3 = 0.f;
        int s = 0;
        for (; s + 4 <= n; s += 4) {
            a0 += z[bk[s] * DD + d];
            a1 += z[bk[s + 1] * DD + d];
            a2 += z[bk[s + 2] * DD + d];
            a3 += z[bk[s + 3] * DD + d];
        }
        for (; s < n; ++s) a0 += z[bk[s] * DD + d];
        zs[w][d] = (a0 + a1) + (a2 + a3);
        __syncthreads();
        float a = 0.f;
        #pragma unroll
        for (int k = 0; k < DD; ++k) a = fmaf(zs[w][k], We1[k * DD + d], a);
        zep[i * DD + d] = tanhf(a);
    }
}

// combine chunk partials -> cstat[c] = colmax + ln(colsum). 32 blocks x (8 cols x 32 lanes)
__global__ __launch_bounds__(256) void smax_finish(
        const float* __restrict__ part, float* __restrict__ cstat) {
    int cg = threadIdx.x >> 5, w = threadIdx.x & 31;
    int c = (blockIdx.x << 3) + cg;
    float m = -3.0e38f, s = 0.f;
    for (int ch = w; ch < NTILES; ch += 32) {
        float m2 = part[ch * 512 + c];
        float s2 = part[ch * 512 + 256 + c];
        float mn = fmaxf(m, m2);
        s = s * expf(m - mn) + s2 * expf(m2 - mn);
        m = mn;
    }
    #pragma unroll
    for (int o = 16; o > 0; o >>= 1) {
        float mo = __shfl_xor(m, o);
        float so = __shfl_xor(s, o);
        float mn = fmaxf(m, mo);
        s = s * expf(m - mn) + so * expf(mo - mn);
        m = mn;
    }
    if (w == 0) cstat[c] = m + logf(s);
}

// normalize S1 + entropy + y2 accumulation (reads precomputed cstat)
__global__ __launch_bounds__(256) void smax_norm(
        float* __restrict__ S, const float* __restrict__ cstat,
        const float* __restrict__ y, float* __restrict__ y2acc,
        float* __restrict__ ent) {
    __shared__ float red[256];
    __shared__ float ybuf[4][64];
    int rt = blockIdx.x % NTILES, ct = blockIdx.x / NTILES;
    int lc = threadIdx.x & 63, q = threadIdx.x >> 6;
    int c = (ct << 6) + lc;
    float mxlns = cstat[c];
    float en = 0.f, ys = 0.f;
    #pragma unroll
    for (int k = 0; k < 16; ++k) {
        int r = (rt << 6) + (k << 2) + q;
        if (r < NN) {
            float v = S[r * PP1 + c];
            float s = expf(v - mxlns);
            S[r * PP1 + c] = s;
            en += s * (mxlns - v);
            ys = fmaf(s, y[r], ys);
        }
    }
    ybuf[q][lc] = ys;
    en = bsum256(en, red);   // syncs cover ybuf visibility
    if (threadIdx.x == 0) atomicAdd(ent, en);
    if (q == 0) atomicAdd(&y2acc[c], ybuf[0][lc] + ybuf[1][lc] + ybuf[2][lc] + ybuf[3][lc]);
}

// fuseD: gather_as (0..4999) | x2 split-K GEMM (5000..5315)  — NO decoder (VGPR!)
__global__ __launch_bounds__(256) void fuseD(
        const int* __restrict__ bucket, const int* __restrict__ deg,
        const float* __restrict__ S1, float* __restrict__ AS1,
        const float* __restrict__ zep, float* __restrict__ PX2,
        float* __restrict__ x2, int roomy) {
    __shared__ __align__(16) float smem[4096];
    int b = blockIdx.x;
    if (b < NN) {
        int i = b, c = threadIdx.x;
        int n = min(deg[i], CAP);
        const int* bk = bucket + i * CAP;
        float a0 = 0.f, a1 = 0.f, a2 = 0.f, a3 = 0.f;
        int s = 0;
        for (; s + 4 <= n; s += 4) {
            a0 += S1[bk[s] * PP1 + c];
            a1 += S1[bk[s + 1] * PP1 + c];
            a2 += S1[bk[s + 2] * PP1 + c];
            a3 += S1[bk[s + 3] * PP1 + c];
        }
        for (; s < n; ++s) a0 += S1[bk[s] * PP1 + c];
        AS1[i * PP1 + c] = (a0 + a1) + (a2 + a3);
    } else {
        int vb2 = b - NN;
        int tile = vb2 & 3, chunk = vb2 >> 2;
        int k0 = chunk * 64, k1 = min(k0 + 64, NN);
        float* dst = roomy ? (PX2 + chunk * (PP1 * DD)) : x2;
        gemm_tile(S1, zep, tile << 6, 0, k0, k1, DD, dst, 1 - roomy,
                  roomy ? 1.f : Y2SCALE, smem);
    }
}

// fuseE: A2 split-K GEMM (0..639) | x2 partial reduce (640..703)
__global__ __launch_bounds__(256) void fuseE(
        const float* __restrict__ S1, const float* __restrict__ AS1,
        float* __restrict__ PA2, float* __restrict__ A2,
        const float* __restrict__ PX2, float* __restrict__ x2, int roomy) {
    __shared__ __align__(16) float smem[4096];
    int b = blockIdx.x;
    if (b < 640) {
        int tile = b & 15, chunk = b >> 4;
        int k0 = chunk * 128, k1 = min(k0 + 128, NN);
        float* dst = roomy ? (PA2 + chunk * (PP1 * PP1)) : A2;
        gemm_tile(S1, AS1, (tile >> 2) << 6, (tile & 3) << 6, k0, k1, PP1,
                  dst, 1 - roomy, 1.f, smem);
    } else if (roomy) {
        int idx = (b - 640) * 256 + threadIdx.x;
        float s = 0.f;
        #pragma unroll 8
        for (int c = 0; c < X2CH; ++c) s += PX2[c * (PP1 * DD) + idx];
        x2[idx] = s * Y2SCALE;
    }
}

// fuseF: A2 partial reduce (0..255) | XW2 + S2 logits (256..351)
__global__ __launch_bounds__(256) void fuseF(
        const float* __restrict__ PA2, float* __restrict__ A2,
        const float* __restrict__ x2, const float* __restrict__ We2,
        const float* __restrict__ Wp2, float* __restrict__ XW2,
        float* __restrict__ S2, int roomy) {
    int b = blockIdx.x;
    int tid = threadIdx.x;
    if (b < 256) {
        if (roomy) {
            int idx = b * 256 + tid;
            float s = 0.f;
            #pragma unroll 8
            for (int c = 0; c < A2CH; ++c) s += PA2[c * (PP1 * PP1) + idx];
            A2[idx] = s;
        }
    } else {
        int gid = (b - 256) * 256 + tid;
        if (gid < PP1 * DD) {
            int i = gid >> 6, j = gid & 63;
            float s = 0.f;
            #pragma unroll
            for (int k = 0; k < DD; ++k) s = fmaf(x2[i * DD + k], We2[k * DD + j], s);
            XW2[gid] = s;
        } else {
            int e = gid - PP1 * DD;
            int i = e >> 5, j = e & 31;
            float s = 0.f;
            #pragma unroll
            for (int k = 0; k < DD; ++k) s = fmaf(x2[i * DD + k], Wp2[k * PP2 + j], s);
            S2[e] = s * LOG_SCALE;
        }
    }
}

// decoder: z-rows (0..624) + x2-rows (625..656); standalone so its 124 VGPR cost is isolated
__global__ __launch_bounds__(256) void decoder8(
        const float* __restrict__ z, const float* __restrict__ x2,
        const float* __restrict__ y, const float* __restrict__ y2acc,
        const float* __restrict__ W1, const float* __restrict__ W2,
        const float* __restrict__ b2, const float* __restrict__ cq,
        float* __restrict__ dres) {
    __shared__ __align__(16) float smem[640];
    int b = blockIdx.x;
    if (b < 625) {
        decoder_rows(z + (b << 3) * DD, y + (b << 3), 1.f, b << 3,
                     W1, W2, b2, cq, dres, smem);
    } else {
        int r8 = b - 625;
        decoder_rows(x2 + (r8 << 3) * DD, y2acc + (r8 << 3), Y2SCALE, NN + (r8 << 3),
                     W1, W2, b2, cq, dres, smem);
    }
}

// fuseH: S2 softmax (+ent2+y3) (0..31) | ze2 = tanh(A2@XW2) (32..95)
__global__ __launch_bounds__(256) void fuseH(
        float* __restrict__ S2, float* __restrict__ ent,
        const float* __restrict__ y2acc, float* __restrict__ y3,
        const float* __restrict__ A2, const float* __restrict__ XW2,
        float* __restrict__ ze2) {
    __shared__ float red[256];
    int t = threadIdx.x;
    if (blockIdx.x < PP2) {
        int p = blockIdx.x;
        float l = S2[t * PP2 + p];
        red[t] = l; __syncthreads();
        #pragma unroll
        for (int o = 128; o > 0; o >>= 1) {
            if (t < o) red[t] = fmaxf(red[t], red[t + o]);
            __syncthreads();
        }
        float mx = red[0]; __syncthreads();
        float ex = expf(l - mx);
        float sum = bsum256(ex, red);
        float lns = logf(sum), inv = 1.f / sum;
        float s = ex * inv;
        S2[t * PP2 + p] = s;
        float en = s * (mx + lns - l);
        float ys = s * y2acc[t];
        en = bsum256(en, red);
        ys = bsum256(ys, red);
        if (t == 0) {
            atomicAdd(ent, en);
            y3[p] = ys * ((32.f / 256.f) * Y2SCALE);
        }
    } else {
        int gid = (blockIdx.x - PP2) * 256 + t;
        int i = gid >> 6, j = gid & 63;
        const float* a = A2 + i * PP1;
        float s = 0.f;
        #pragma unroll 16
        for (int k = 0; k < PP1; ++k) s = fmaf(a[k], XW2[k * DD + j], s);
        ze2[gid] = tanhf(s);
    }
}

// tail (4 blocks): compute 8 x3 rows in LDS, decode them, last block reduces the loss
__global__ __launch_bounds__(256) void tail(
        const float* __restrict__ S2, const float* __restrict__ ze2,
        const float* __restrict__ y3,
        const float* __restrict__ W1, const float* __restrict__ W2,
        const float* __restrict__ b2, const float* __restrict__ cq,
        float* __restrict__ dres, int* __restrict__ cnt,
        const float* __restrict__ acc, float* __restrict__ out) {
    __shared__ __align__(16) float smem[1152];   // [0..511] x3 rows, [512..] decoder scratch
    __shared__ int lastflag;
    int t = threadIdx.x;
    int jbase = blockIdx.x << 3;
    #pragma unroll
    for (int kk = 0; kk < 2; ++kk) {
        int idx = t + kk * 256;
        int jl = idx >> 6, d = idx & 63;
        int j = jbase + jl;
        float a = 0.f;
        for (int i = 0; i < PP1; ++i)
            a = fmaf(S2[i * PP2 + j], ze2[i * DD + d], a);
        smem[idx] = a * (32.f / 256.f);
    }
    __syncthreads();
    decoder_rows(smem, y3 + jbase, 1.f, NN + PP1 + jbase,
                 W1, W2, b2, cq, dres, smem + 512);
    if (t < 8) __threadfence();
    __syncthreads();
    if (t == 0) lastflag = atomicAdd(cnt, 1);
    __syncthreads();
    if (lastflag == 3) {
        __threadfence();
        float* red = smem;
        float sd = 0.f, sp = 0.f;
        for (int i = t; i < MM; i += 256) {
            sd += dres[i * 2];
            sp += dres[i * 2 + 1];
        }
        sd = bsum256(sd, red);
        sp = bsum256(sp, red);
        if (t == 0)
            out[0] = sd * (1.f / MM) + sp * (1.f / MM)
                   + acc[2] * (1.f / (float)(NN * PP1)) + acc[3] * (1.f / (float)(PP1 * PP2));
    }
}

extern "C" void kernel_launch(void* const* d_in, const int* in_sizes, int n_in,
                              void* d_out, int out_size, void* d_ws, size_t ws_size,
                              hipStream_t stream) {
    const float* x0   = (const float*)d_in[0];
    const int*   adj  = (const int*)d_in[1];
    const float* t    = (const float*)d_in[2];
    const float* y    = (const float*)d_in[3];
    const float* Wenc = (const float*)d_in[4];
    const float* Wp1  = (const float*)d_in[5];
    const float* Wp2  = (const float*)d_in[6];
    const float* We1  = (const float*)d_in[7];
    const float* We2  = (const float*)d_in[8];
    const float* W1   = (const float*)d_in[9];
    const float* b1   = (const float*)d_in[10];
    const float* W2   = (const float*)d_in[11];
    const float* b2   = (const float*)d_in[12];

    char* ws = (char*)d_ws;
    float* acc   = (float*)(ws + ACC_OFF);
    int*   cnt   = (int*)(ws + CNT_OFF);
    int*   deg   = (int*)(ws + DEG_OFF);
    float* y2acc = (float*)(ws + Y2A_OFF);
    float* x2    = (float*)(ws + X2_OFF);
    float* A2    = (float*)(ws + A2_OFF);
    unsigned int* mask = (unsigned int*)(ws + BM_OFF);
    float* part  = (float*)(ws + PART_OFF);
    float* cstat = (float*)(ws + CSTAT_OFF);
    float* XW2   = (float*)(ws + XW2_OFF);
    float* S2    = (float*)(ws + S2_OFF);
    float* ze2   = (float*)(ws + ZE2_OFF);
    float* y3    = (float*)(ws + Y3_OFF);
    int*   buck  = (int*)(ws + BUCK_OFF);
    float* zep   = (float*)(ws + ZEP_OFF);
    float* z     = (float*)(ws + Z_OFF);
    float* S1    = (float*)(ws + S1_OFF);
    float* AS1   = (float*)(ws + AS1_OFF);
    float* cq    = (float*)(ws + CQ_OFF);
    float* dres  = (float*)(ws + DRES_OFF);
    float* PA2   = (float*)(ws + PA2_OFF);
    float* PX2   = (float*)(ws + PX2_OFF);
    int roomy = (ws_size >= WS_ROOMY) ? 1 : 0;

    hipMemsetAsync(ws, 0, ZERO_BYTES, stream);

    stage0<<<1564, 256, 0, stream>>>(x0, Wenc, z, adj, mask, buck, deg, t, W1, b1, cq);
    stage1<<<NTILES * 4 + NN / 4, 256, 0, stream>>>(z, Wp1, S1, part, buck, deg, We1, zep);
    smax_finish<<<32, 256, 0, stream>>>(part, cstat);
    smax_norm<<<NTILES * 4, 256, 0, stream>>>(S1, cstat, y, y2acc, &acc[2]);
    fuseD<<<NN + 316, 256, 0, stream>>>(buck, deg, S1, AS1, zep, PX2, x2, roomy);
    fuseE<<<704, 256, 0, stream>>>(S1, AS1, PA2, A2, PX2, x2, roomy);
    fuseF<<<384, 256, 0, stream>>>(PA2, A2, x2, We2, Wp2, XW2, S2, roomy);
    decoder8<<<657, 256, 0, stream>>>(z, x2, y, y2acc, W1, W2, b2, cq, dres);
    fuseH<<<96, 256, 0, stream>>>(S2, &acc[3], y2acc, y3, A2, XW2, ze2);
    tail<<<4, 256, 0, stream>>>(S2, ze2, y3, W1, W2, b2, cq,
                                dres, cnt, acc, (float*)d_out);
}